// Round 2
// baseline (264.039 us; speedup 1.0000x reference)
//
#include <hip/hip_runtime.h>

// Attention over channel dim: B=16, HW=16384, C=64, fp32.
// scores[b,q,k] = sum_hw Q[b,hw,q]*K[b,hw,k]; attn=softmax_k; out[b,hw,q]=sum_k attn[b,q,k]*V[b,hw,k]
//
// ws layout: partial scores [B][S_SPLIT][64][64] fp32 (8 MB), then attn [B][64][64] fp32 (256 KB).

#define S_SPLIT 32
#define CHUNK (16384 / S_SPLIT)   // 512 rows per split block
#define TILE_ROWS 32              // rows staged in LDS per iteration

// ---------------- Kernel A: partial scores (split-K GEMM, 8x8 register tile) ----------------
// All 4 waves compute the SAME 64x64 (q,k) tile over DISJOINT row subsets
// (r = i*4 + w), so each wave holds a 1/4-partial accumulator. A 2-step LDS
// tree reduction combines them before the single coalesced global store.
__global__ __launch_bounds__(256) void scores_kernel(
    const float* __restrict__ Q, const float* __restrict__ K,
    float* __restrict__ partial) {
  const int bs = blockIdx.x;            // b * S_SPLIT + s
  const int b = bs / S_SPLIT;
  const int s = bs % S_SPLIT;
  const int tid = threadIdx.x;
  const int w = tid >> 6;               // wave id 0..3
  const int l = tid & 63;               // lane
  const int q0 = (l >> 3) * 8;          // 8 q per lane
  const int k0 = (l & 7) * 8;           // 8 k per lane

  __shared__ union {
    struct { float4 q[TILE_ROWS * 16]; float4 k[TILE_ROWS * 16]; } t;  // 16 KB
    float red[2][4096];                                                // 32 KB
  } lds;

  float acc[8][8];
#pragma unroll
  for (int i = 0; i < 8; ++i)
#pragma unroll
    for (int j = 0; j < 8; ++j) acc[i][j] = 0.f;

  const float4* Qg = (const float4*)(Q + ((size_t)b * 16384 + (size_t)s * CHUNK) * 64);
  const float4* Kg = (const float4*)(K + ((size_t)b * 16384 + (size_t)s * CHUNK) * 64);

  for (int t = 0; t < CHUNK / TILE_ROWS; ++t) {
    __syncthreads();   // protect previous tile's reads before overwrite
    // stage 32 rows of Q and K (512 float4 each), fully coalesced
    lds.t.q[tid]       = Qg[t * 512 + tid];
    lds.t.q[tid + 256] = Qg[t * 512 + tid + 256];
    lds.t.k[tid]       = Kg[t * 512 + tid];
    lds.t.k[tid + 256] = Kg[t * 512 + tid + 256];
    __syncthreads();

#pragma unroll
    for (int i = 0; i < 8; ++i) {
      const int r = (i << 2) + w;       // wave w handles rows w,4+w,...,28+w
      float4 qa = lds.t.q[r * 16 + (q0 >> 2)];
      float4 qb = lds.t.q[r * 16 + (q0 >> 2) + 1];
      float4 ka = lds.t.k[r * 16 + (k0 >> 2)];
      float4 kb = lds.t.k[r * 16 + (k0 >> 2) + 1];
      float qv[8] = {qa.x, qa.y, qa.z, qa.w, qb.x, qb.y, qb.z, qb.w};
      float kv[8] = {ka.x, ka.y, ka.z, ka.w, kb.x, kb.y, kb.z, kb.w};
#pragma unroll
      for (int ii = 0; ii < 8; ++ii)
#pragma unroll
        for (int jj = 0; jj < 8; ++jj)
          acc[ii][jj] += qv[ii] * kv[jj];
    }
  }

  // ---- cross-wave reduction: waves 2,3 publish; waves 0,1 add; halves summed on store ----
  __syncthreads();                      // all waves done reading tile LDS
  if (w >= 2) {
    float4* dst = (float4*)lds.red[w - 2];
#pragma unroll
    for (int i = 0; i < 8; ++i) {
      dst[(q0 + i) * 16 + (k0 >> 2)]     = make_float4(acc[i][0], acc[i][1], acc[i][2], acc[i][3]);
      dst[(q0 + i) * 16 + (k0 >> 2) + 1] = make_float4(acc[i][4], acc[i][5], acc[i][6], acc[i][7]);
    }
  }
  __syncthreads();
  if (w < 2) {
    float4* dst = (float4*)lds.red[w];
#pragma unroll
    for (int i = 0; i < 8; ++i) {
      float4 u = dst[(q0 + i) * 16 + (k0 >> 2)];
      float4 v = dst[(q0 + i) * 16 + (k0 >> 2) + 1];
      dst[(q0 + i) * 16 + (k0 >> 2)]     = make_float4(u.x + acc[i][0], u.y + acc[i][1], u.z + acc[i][2], u.w + acc[i][3]);
      dst[(q0 + i) * 16 + (k0 >> 2) + 1] = make_float4(v.x + acc[i][4], v.y + acc[i][5], v.z + acc[i][6], v.w + acc[i][7]);
    }
  }
  __syncthreads();
  // cooperative coalesced store of the reduced 64x64 tile
  float4* p4 = (float4*)(partial + (size_t)bs * 4096);
  const float4* r0 = (const float4*)lds.red[0];
  const float4* r1 = (const float4*)lds.red[1];
#pragma unroll
  for (int c = 0; c < 4; ++c) {
    float4 x = r0[c * 256 + tid];
    float4 y = r1[c * 256 + tid];
    p4[c * 256 + tid] = make_float4(x.x + y.x, x.y + y.y, x.z + y.z, x.w + y.w);
  }
}

// ---------------- Kernel B: reduce partials + softmax over k ----------------
__global__ __launch_bounds__(64) void softmax_kernel(
    const float* __restrict__ partial, float* __restrict__ attn) {
  const int bq = blockIdx.x;            // b*64 + q
  const int b = bq >> 6;
  const int q = bq & 63;
  const int k = threadIdx.x;            // lane = k

  float v = 0.f;
  for (int s = 0; s < S_SPLIT; ++s)
    v += partial[((size_t)(b * S_SPLIT + s) * 64 + q) * 64 + k];

  float m = v;
#pragma unroll
  for (int off = 32; off > 0; off >>= 1)
    m = fmaxf(m, __shfl_xor(m, off, 64));
  float e = __expf(v - m);
  float sum = e;
#pragma unroll
  for (int off = 32; off > 0; off >>= 1)
    sum += __shfl_xor(sum, off, 64);
  attn[(size_t)bq * 64 + k] = e / sum;
}

// ---------------- Kernel C: out = attn * V (lane=q, V-row broadcast from LDS) ----------------
__global__ __launch_bounds__(256) void out_kernel(
    const float* __restrict__ V, const float* __restrict__ attn,
    float* __restrict__ out) {
  const int blk = blockIdx.x;
  const int b = blk >> 8;               // 256 tiles of 64 rows per batch
  const int tile = blk & 255;
  const int tid = threadIdx.x;
  const int w = tid >> 6;
  const int l = tid & 63;               // lane = q

  __shared__ float4 ldsV[64 * 16];      // 64 rows x 64 fp32 = 16 KB

  // attn row for q = l into registers (64 VGPRs)
  float a[64];
  const float4* arow = (const float4*)(attn + ((size_t)b * 64 + l) * 64);
#pragma unroll
  for (int j = 0; j < 16; ++j) {
    float4 t = arow[j];
    a[4 * j]     = t.x;
    a[4 * j + 1] = t.y;
    a[4 * j + 2] = t.z;
    a[4 * j + 3] = t.w;
  }

  const float4* Vg = (const float4*)(V + ((size_t)b * 16384 + (size_t)tile * 64) * 64);
#pragma unroll
  for (int c = 0; c < 4; ++c)
    ldsV[c * 256 + tid] = Vg[c * 256 + tid];
  __syncthreads();

  float* outg = out + ((size_t)b * 16384 + (size_t)tile * 64) * 64;
  for (int i = 0; i < 16; ++i) {
    const int r = w * 16 + i;           // each wave owns 16 rows
    float acc = 0.f;
#pragma unroll
    for (int j = 0; j < 16; ++j) {
      float4 v = ldsV[r * 16 + j];      // wave-uniform address -> broadcast read
      acc += a[4 * j] * v.x + a[4 * j + 1] * v.y + a[4 * j + 2] * v.z + a[4 * j + 3] * v.w;
    }
    outg[(size_t)r * 64 + l] = acc;     // coalesced 256 B per wave
  }
}

extern "C" void kernel_launch(void* const* d_in, const int* in_sizes, int n_in,
                              void* d_out, int out_size, void* d_ws, size_t ws_size,
                              hipStream_t stream) {
  const float* Q = (const float*)d_in[0];
  const float* K = (const float*)d_in[1];
  const float* V = (const float*)d_in[2];
  float* out = (float*)d_out;

  float* partial = (float*)d_ws;                         // 16*S_SPLIT*4096 floats = 8 MB
  float* attn = partial + (size_t)16 * S_SPLIT * 4096;   // 256 KB

  scores_kernel<<<16 * S_SPLIT, 256, 0, stream>>>(Q, K, partial);
  softmax_kernel<<<16 * 64, 64, 0, stream>>>(partial, attn);
  out_kernel<<<16 * 256, 256, 0, stream>>>(V, attn, out);
}